// Round 1
// baseline (2220.045 us; speedup 1.0000x reference)
//
#include <hip/hip_runtime.h>
#include <math.h>

#define BB 256
#define TT 2048
#define FF 2
#define HH 128
#define OO 2
#define NTHREADS 384

__device__ __forceinline__ float fast_rcp(float x) { return __builtin_amdgcn_rcpf(x); }
__device__ __forceinline__ float sigmoid_f(float x) { return fast_rcp(1.0f + __expf(-x)); }
__device__ __forceinline__ float tanh_f(float x) { return 1.0f - 2.0f * fast_rcp(1.0f + __expf(2.0f * x)); }

__global__ __launch_bounds__(NTHREADS, 1)
void gru_persistent(const float* __restrict__ x, const float* __restrict__ h0,
                    const float* __restrict__ Wir, const float* __restrict__ Wiz,
                    const float* __restrict__ Win, const float* __restrict__ Whr,
                    const float* __restrict__ Whz, const float* __restrict__ Whn,
                    const float* __restrict__ bhr, const float* __restrict__ bhz,
                    const float* __restrict__ bhn, const float* __restrict__ Wd,
                    const float* __restrict__ bd, float* __restrict__ out)
{
    // out layout: [carry B*H][y B*T*O]
    __shared__ float x_sh[TT * FF];                 // 16 KB
    __shared__ __align__(16) float h_sh[HH];
    __shared__ float rbuf[HH], zbuf[HH], mbuf[HH];
    __shared__ float pbuf[4];

    const int b   = blockIdx.x;
    const int tid = threadIdx.x;
    const int g   = tid >> 7;        // 0:r 1:z 2:n  (wave-uniform: 2 waves per gate)
    const int j   = tid & (HH - 1);

    const float* Wh = (g == 0) ? Whr : (g == 1) ? Whz : Whn;
    const float* Wi = (g == 0) ? Wir : (g == 1) ? Wiz : Win;
    const float* bh = (g == 0) ? bhr : (g == 1) ? bhz : bhn;

    // cache one weight column in registers (128 VGPRs)
    float w[HH];
    #pragma unroll
    for (int k = 0; k < HH; ++k) w[k] = Wh[k * HH + j];
    const float wi0  = Wi[0 * HH + j];
    const float wi1  = Wi[1 * HH + j];
    const float bias = bh[j];

    // combiner threads (g==0, tid<128) extras
    float win0 = 0.f, win1 = 0.f, wd0 = 0.f, wd1 = 0.f;
    if (g == 0) {
        win0 = Win[0 * HH + j];
        win1 = Win[1 * HH + j];
        wd0  = Wd[j * OO + 0];
        wd1  = Wd[j * OO + 1];
    }
    const float bd0 = bd[0], bd1 = bd[1];

    // stage x row and h0
    for (int i = tid; i < TT * FF; i += NTHREADS) x_sh[i] = x[b * (TT * FF) + i];
    if (tid < HH) h_sh[tid] = h0[b * HH + tid];
    __syncthreads();

    float* __restrict__ yout = out + BB * HH;

    for (int t = 0; t < TT; ++t) {
        const float x0 = x_sh[t * FF + 0];
        const float x1 = x_sh[t * FF + 1];

        // ---- phase 1: per-gate GEMV (all 384 threads) ----
        float a0 = bias, a1 = 0.f, a2 = 0.f, a3 = 0.f;
        if (g != 2) a0 += x0 * wi0 + x1 * wi1;   // n-gate excludes input proj (added after r*)
        #pragma unroll
        for (int kk = 0; kk < HH / 4; ++kk) {
            const float4 h4 = reinterpret_cast<const float4*>(h_sh)[kk];
            a0 = fmaf(h4.x, w[4 * kk + 0], a0);
            a1 = fmaf(h4.y, w[4 * kk + 1], a1);
            a2 = fmaf(h4.z, w[4 * kk + 2], a2);
            a3 = fmaf(h4.w, w[4 * kk + 3], a3);
        }
        const float acc = (a0 + a1) + (a2 + a3);

        if (g == 0)      rbuf[j] = acc;
        else if (g == 1) zbuf[j] = acc;
        else             mbuf[j] = acc;         // m = h@Whn + bhn (no gn, no r yet)

        // thread 0 stores previous step's y (pbuf from step t-1; ordered by barriers)
        if (tid == 0 && t > 0) {
            const long idx = ((long)b * TT + (t - 1)) * OO;
            yout[idx + 0] = pbuf[0] + pbuf[2] + bd0;
            yout[idx + 1] = pbuf[1] + pbuf[3] + bd1;
        }
        __syncthreads();   // barrier A: gate buffers visible

        // ---- phase 2: combine (threads 0..127, waves 0-1) ----
        if (g == 0) {
            const float r  = sigmoid_f(rbuf[j]);
            const float z  = sigmoid_f(zbuf[j]);
            const float gn = x0 * win0 + x1 * win1;
            const float n  = tanh_f(gn + r * mbuf[j]);
            const float hn = (1.0f - z) * n + z * h_sh[j];
            h_sh[j] = hn;

            // fused output projection: y[t] = h_new @ Wd + bd  (O=2)
            float p0 = hn * wd0;
            float p1 = hn * wd1;
            #pragma unroll
            for (int off = 32; off >= 1; off >>= 1) {
                p0 += __shfl_down(p0, off);
                p1 += __shfl_down(p1, off);
            }
            if ((tid & 63) == 0) {
                pbuf[(tid >> 6) * 2 + 0] = p0;
                pbuf[(tid >> 6) * 2 + 1] = p1;
            }
        }
        __syncthreads();   // barrier B: h_new + partials visible
    }

    // tail: y[T-1] and carry
    if (tid == 0) {
        const long idx = ((long)b * TT + (TT - 1)) * OO;
        yout[idx + 0] = pbuf[0] + pbuf[2] + bd0;
        yout[idx + 1] = pbuf[1] + pbuf[3] + bd1;
    }
    if (tid < HH) out[b * HH + tid] = h_sh[tid];
}

extern "C" void kernel_launch(void* const* d_in, const int* in_sizes, int n_in,
                              void* d_out, int out_size, void* d_ws, size_t ws_size,
                              hipStream_t stream) {
    const float* x   = (const float*)d_in[0];
    const float* h0  = (const float*)d_in[1];
    const float* Wir = (const float*)d_in[2];
    const float* Wiz = (const float*)d_in[3];
    const float* Win = (const float*)d_in[4];
    const float* Whr = (const float*)d_in[5];
    const float* Whz = (const float*)d_in[6];
    const float* Whn = (const float*)d_in[7];
    const float* bhr = (const float*)d_in[8];
    const float* bhz = (const float*)d_in[9];
    const float* bhn = (const float*)d_in[10];
    const float* Wd  = (const float*)d_in[11];
    const float* bd  = (const float*)d_in[12];
    float* out = (float*)d_out;

    gru_persistent<<<BB, NTHREADS, 0, stream>>>(x, h0, Wir, Wiz, Win, Whr, Whz, Whn,
                                                bhr, bhz, bhn, Wd, bd, out);
}

// Round 2
// 2104.078 us; speedup vs baseline: 1.0551x; 1.0551x over previous
//
#include <hip/hip_runtime.h>
#include <math.h>

#define BB 256
#define TT 2048
#define FF 2
#define HH 128
#define OO 2
#define NT 768   // 12 waves: 3 gates x 2 column-halves x 2 waves(128 threads)

__device__ __forceinline__ float fast_rcp(float x) { return __builtin_amdgcn_rcpf(x); }
__device__ __forceinline__ float sigmoid_f(float x) { return fast_rcp(1.0f + __expf(-x)); }
__device__ __forceinline__ float tanh_f(float x) { return 1.0f - 2.0f * fast_rcp(1.0f + __expf(2.0f * x)); }

__global__ __launch_bounds__(NT, 3)
void gru_persistent(const float* __restrict__ x, const float* __restrict__ h0,
                    const float* __restrict__ Wir, const float* __restrict__ Wiz,
                    const float* __restrict__ Win, const float* __restrict__ Whr,
                    const float* __restrict__ Whz, const float* __restrict__ Whn,
                    const float* __restrict__ bhr, const float* __restrict__ bhz,
                    const float* __restrict__ bhn, const float* __restrict__ Wd,
                    const float* __restrict__ bd, float* __restrict__ out)
{
    // out layout: [carry B*H][y B*T*O]
    __shared__ float x_sh[TT * FF];                 // 16 KB
    __shared__ __align__(16) float h_sh[HH];
    __shared__ float part[3][2][HH];                // gate x half x j partials

    const int b    = blockIdx.x;
    const int tid  = threadIdx.x;
    const int g    = tid >> 8;          // 0:r 1:z 2:n   (4 waves per gate)
    const int c    = (tid >> 7) & 1;    // column half   (2 waves per half)
    const int j    = tid & (HH - 1);    // output column
    const int wv   = tid >> 6;          // wave id 0..11
    const int lane = tid & 63;

    const float* Wh = (g == 0) ? Whr : (g == 1) ? Whz : Whn;
    const float* Wi = (g == 0) ? Wir : (g == 1) ? Wiz : Win;
    const float* bh = (g == 0) ? bhr : (g == 1) ? bhz : bhn;

    // half weight column in registers (64 VGPRs), pinned so the compiler
    // cannot rematerialize the global loads inside the t-loop
    float w[64];
    #pragma unroll
    for (int k = 0; k < 64; ++k) w[k] = Wh[(c * 64 + k) * HH + j];
    #pragma unroll
    for (int k = 0; k < 64; ++k) asm volatile("" : "+v"(w[k]));

    const float gbias = (c == 0) ? bh[j] : 0.0f;
    float wi0 = 0.0f, wi1 = 0.0f;
    if (c == 0 && g != 2) { wi0 = Wi[0 * HH + j]; wi1 = Wi[1 * HH + j]; }

    // combine-thread extras (tid < 128)
    float win0 = 0.0f, win1 = 0.0f;
    if (tid < HH) { win0 = Win[0 * HH + j]; win1 = Win[1 * HH + j]; }

    // y-wave (wave 8) extras: Wd columns for this lane's two h entries
    float wdA0 = 0.f, wdA1 = 0.f, wdB0 = 0.f, wdB1 = 0.f;
    if (wv == 8) {
        wdA0 = Wd[lane * OO + 0];        wdA1 = Wd[lane * OO + 1];
        wdB0 = Wd[(lane + 64) * OO + 0]; wdB1 = Wd[(lane + 64) * OO + 1];
    }
    const float bd0 = bd[0], bd1 = bd[1];

    // stage x row (float4) and h0
    {
        const float4* xi = reinterpret_cast<const float4*>(x + (size_t)b * TT * FF);
        float4* xo = reinterpret_cast<float4*>(x_sh);
        for (int i = tid; i < TT * FF / 4; i += NT) xo[i] = xi[i];
    }
    if (tid < HH) h_sh[tid] = h0[b * HH + tid];
    __syncthreads();

    float* __restrict__ yout = out + BB * HH;

    for (int t = 0; t < TT; ++t) {
        const float x0 = x_sh[t * FF + 0];
        const float x1 = x_sh[t * FF + 1];

        // ---- phase 1: per-gate half-column GEMV (all 768 threads) ----
        float a0 = gbias + x0 * wi0 + x1 * wi1;   // wi==0 where not applicable
        float a1 = 0.f, a2 = 0.f, a3 = 0.f;
        const float4* hp = reinterpret_cast<const float4*>(h_sh + c * 64);
        #pragma unroll
        for (int kk = 0; kk < 16; ++kk) {
            const float4 h4 = hp[kk];
            a0 = fmaf(h4.x, w[4 * kk + 0], a0);
            a1 = fmaf(h4.y, w[4 * kk + 1], a1);
            a2 = fmaf(h4.z, w[4 * kk + 2], a2);
            a3 = fmaf(h4.w, w[4 * kk + 3], a3);
        }
        part[g][c][j] = (a0 + a1) + (a2 + a3);

        // wave 8 additionally emits y[t-1] from h_sh (read-only in phase 1)
        if (wv == 8 && t > 0) {
            const float hv0 = h_sh[lane], hv1 = h_sh[lane + 64];
            float p0 = hv0 * wdA0 + hv1 * wdB0;
            float p1 = hv0 * wdA1 + hv1 * wdB1;
            #pragma unroll
            for (int off = 32; off >= 1; off >>= 1) {
                p0 += __shfl_xor(p0, off);
                p1 += __shfl_xor(p1, off);
            }
            if (lane == 0)
                reinterpret_cast<float2*>(yout)[(size_t)b * TT + (t - 1)] =
                    make_float2(p0 + bd0, p1 + bd1);
        }
        __syncthreads();   // barrier A: partials visible

        // ---- phase 2: combine (threads 0..127) ----
        if (tid < HH) {
            const float racc = part[0][0][j] + part[0][1][j];
            const float zacc = part[1][0][j] + part[1][1][j];
            const float macc = part[2][0][j] + part[2][1][j];
            const float r  = sigmoid_f(racc);
            const float z  = sigmoid_f(zacc);
            const float n  = tanh_f(x0 * win0 + x1 * win1 + r * macc);
            h_sh[j] = (1.0f - z) * n + z * h_sh[j];
        }
        __syncthreads();   // barrier B: h_new visible
    }

    // tail: y[T-1] and carry
    if (wv == 8) {
        const float hv0 = h_sh[lane], hv1 = h_sh[lane + 64];
        float p0 = hv0 * wdA0 + hv1 * wdB0;
        float p1 = hv0 * wdA1 + hv1 * wdB1;
        #pragma unroll
        for (int off = 32; off >= 1; off >>= 1) {
            p0 += __shfl_xor(p0, off);
            p1 += __shfl_xor(p1, off);
        }
        if (lane == 0)
            reinterpret_cast<float2*>(yout)[(size_t)b * TT + (TT - 1)] =
                make_float2(p0 + bd0, p1 + bd1);
    }
    if (tid < HH) out[b * HH + tid] = h_sh[tid];
}

extern "C" void kernel_launch(void* const* d_in, const int* in_sizes, int n_in,
                              void* d_out, int out_size, void* d_ws, size_t ws_size,
                              hipStream_t stream) {
    const float* x   = (const float*)d_in[0];
    const float* h0  = (const float*)d_in[1];
    const float* Wir = (const float*)d_in[2];
    const float* Wiz = (const float*)d_in[3];
    const float* Win = (const float*)d_in[4];
    const float* Whr = (const float*)d_in[5];
    const float* Whz = (const float*)d_in[6];
    const float* Whn = (const float*)d_in[7];
    const float* bhr = (const float*)d_in[8];
    const float* bhz = (const float*)d_in[9];
    const float* bhn = (const float*)d_in[10];
    const float* Wd  = (const float*)d_in[11];
    const float* bd  = (const float*)d_in[12];
    float* out = (float*)d_out;

    gru_persistent<<<BB, NT, 0, stream>>>(x, h0, Wir, Wiz, Win, Whr, Whz, Whn,
                                          bhr, bhz, bhn, Wd, bd, out);
}

// Round 3
// 2078.914 us; speedup vs baseline: 1.0679x; 1.0121x over previous
//
#include <hip/hip_runtime.h>
#include <math.h>

#define BB 256
#define TT 2048
#define FF 2
#define HH 128
#define OO 2
#define NT 768   // 12 waves: 3 gates x 2 column-halves x 2 waves(128 threads)

typedef float f32x16 __attribute__((ext_vector_type(16)));

__device__ __forceinline__ float fast_rcp(float x) { return __builtin_amdgcn_rcpf(x); }
__device__ __forceinline__ float sigmoid_f(float x) { return fast_rcp(1.0f + __expf(-x)); }
__device__ __forceinline__ float tanh_f(float x) { return 1.0f - 2.0f * fast_rcp(1.0f + __expf(2.0f * x)); }

__global__ __launch_bounds__(NT, 3)
void gru_persistent(const float* __restrict__ x, const float* __restrict__ h0,
                    const float* __restrict__ Wir, const float* __restrict__ Wiz,
                    const float* __restrict__ Win, const float* __restrict__ Whr,
                    const float* __restrict__ Whz, const float* __restrict__ Whn,
                    const float* __restrict__ bhr, const float* __restrict__ bhz,
                    const float* __restrict__ bhn, const float* __restrict__ Wd,
                    const float* __restrict__ bd, float* __restrict__ out)
{
    // out layout: [carry B*H][y B*T*O]
    __shared__ float x_sh[TT * FF];                 // 16 KB
    __shared__ __align__(16) float h_sh[HH];
    __shared__ float part[3][2][HH];                // gate x half x j partials

    const int b    = blockIdx.x;
    const int tid  = threadIdx.x;
    const int g    = tid >> 8;          // 0:r 1:z 2:n   (4 waves per gate)
    const int c    = (tid >> 7) & 1;    // column half   (2 waves per half)
    const int j    = tid & (HH - 1);    // output column
    const int wv   = tid >> 6;          // wave id 0..11
    const int lane = tid & 63;

    const float* Wh = (g == 0) ? Whr : (g == 1) ? Whz : Whn;
    const float* Wi = (g == 0) ? Wir : (g == 1) ? Wiz : Win;
    const float* bh = (g == 0) ? bhr : (g == 1) ? bhz : bhn;

    // half weight column in NAMED vector registers (64 VGPRs total).
    // ext_vector values with constant indices stay in registers (no array,
    // no scratch); the whole-vector asm pin below makes remat impossible.
    f32x16 wv0, wv1, wv2, wv3;
    {
        const float* Wcol = Wh + j;     // column j, row stride HH
        #pragma unroll
        for (int k = 0; k < 16; ++k) {
            wv0[k] = Wcol[(c * 64 + k     ) * HH];
            wv1[k] = Wcol[(c * 64 + k + 16) * HH];
            wv2[k] = Wcol[(c * 64 + k + 32) * HH];
            wv3[k] = Wcol[(c * 64 + k + 48) * HH];
        }
    }
    asm volatile("" : "+v"(wv0), "+v"(wv1), "+v"(wv2), "+v"(wv3));

    const float gbias = (c == 0) ? bh[j] : 0.0f;
    float wi0 = 0.0f, wi1 = 0.0f;
    if (c == 0 && g != 2) { wi0 = Wi[0 * HH + j]; wi1 = Wi[1 * HH + j]; }

    // combine-thread extras (tid < 128)
    float win0 = 0.0f, win1 = 0.0f;
    if (tid < HH) { win0 = Win[0 * HH + j]; win1 = Win[1 * HH + j]; }

    // y-wave (wave 8) extras: Wd columns for this lane's two h entries
    float wdA0 = 0.f, wdA1 = 0.f, wdB0 = 0.f, wdB1 = 0.f;
    if (wv == 8) {
        wdA0 = Wd[lane * OO + 0];        wdA1 = Wd[lane * OO + 1];
        wdB0 = Wd[(lane + 64) * OO + 0]; wdB1 = Wd[(lane + 64) * OO + 1];
    }
    const float bd0 = bd[0], bd1 = bd[1];

    // stage x row (float4) and h0
    {
        const float4* xi = reinterpret_cast<const float4*>(x + (size_t)b * TT * FF);
        float4* xo = reinterpret_cast<float4*>(x_sh);
        for (int i = tid; i < TT * FF / 4; i += NT) xo[i] = xi[i];
    }
    if (tid < HH) h_sh[tid] = h0[b * HH + tid];
    __syncthreads();

    float* __restrict__ yout = out + BB * HH;

    // 16 FMAs against one named weight vector; kk is unrolled -> all vector
    // extracts use compile-time-constant indices (register-resident).
    #define DOT16(WV, OFS)                                         \
        {                                                          \
            _Pragma("unroll")                                      \
            for (int kk = 0; kk < 4; ++kk) {                       \
                const float4 h4 = hp[(OFS) / 4 + kk];              \
                a0 = fmaf(h4.x, WV[4 * kk + 0], a0);               \
                a1 = fmaf(h4.y, WV[4 * kk + 1], a1);               \
                a2 = fmaf(h4.z, WV[4 * kk + 2], a2);               \
                a3 = fmaf(h4.w, WV[4 * kk + 3], a3);               \
            }                                                      \
        }

    for (int t = 0; t < TT; ++t) {
        const float x0 = x_sh[t * FF + 0];
        const float x1 = x_sh[t * FF + 1];

        // ---- phase 1: per-gate half-column GEMV (all 768 threads) ----
        float a0 = gbias + x0 * wi0 + x1 * wi1;   // wi==0 where not applicable
        float a1 = 0.f, a2 = 0.f, a3 = 0.f;
        const float4* hp = reinterpret_cast<const float4*>(h_sh + c * 64);
        DOT16(wv0, 0)
        DOT16(wv1, 16)
        DOT16(wv2, 32)
        DOT16(wv3, 48)
        part[g][c][j] = (a0 + a1) + (a2 + a3);

        // wave 8 additionally emits y[t-1] from h_sh (read-only in phase 1)
        if (wv == 8 && t > 0) {
            const float hv0 = h_sh[lane], hv1 = h_sh[lane + 64];
            float p0 = hv0 * wdA0 + hv1 * wdB0;
            float p1 = hv0 * wdA1 + hv1 * wdB1;
            #pragma unroll
            for (int off = 32; off >= 1; off >>= 1) {
                p0 += __shfl_xor(p0, off);
                p1 += __shfl_xor(p1, off);
            }
            if (lane == 0)
                reinterpret_cast<float2*>(yout)[(size_t)b * TT + (t - 1)] =
                    make_float2(p0 + bd0, p1 + bd1);
        }
        __syncthreads();   // barrier A: partials visible

        // ---- phase 2: combine (threads 0..127) ----
        if (tid < HH) {
            const float racc = part[0][0][j] + part[0][1][j];
            const float zacc = part[1][0][j] + part[1][1][j];
            const float macc = part[2][0][j] + part[2][1][j];
            const float r  = sigmoid_f(racc);
            const float z  = sigmoid_f(zacc);
            const float n  = tanh_f(x0 * win0 + x1 * win1 + r * macc);
            h_sh[j] = (1.0f - z) * n + z * h_sh[j];
        }
        __syncthreads();   // barrier B: h_new visible
    }

    // tail: y[T-1] and carry
    if (wv == 8) {
        const float hv0 = h_sh[lane], hv1 = h_sh[lane + 64];
        float p0 = hv0 * wdA0 + hv1 * wdB0;
        float p1 = hv0 * wdA1 + hv1 * wdB1;
        #pragma unroll
        for (int off = 32; off >= 1; off >>= 1) {
            p0 += __shfl_xor(p0, off);
            p1 += __shfl_xor(p1, off);
        }
        if (lane == 0)
            reinterpret_cast<float2*>(yout)[(size_t)b * TT + (TT - 1)] =
                make_float2(p0 + bd0, p1 + bd1);
    }
    if (tid < HH) out[b * HH + tid] = h_sh[tid];
}

extern "C" void kernel_launch(void* const* d_in, const int* in_sizes, int n_in,
                              void* d_out, int out_size, void* d_ws, size_t ws_size,
                              hipStream_t stream) {
    const float* x   = (const float*)d_in[0];
    const float* h0  = (const float*)d_in[1];
    const float* Wir = (const float*)d_in[2];
    const float* Wiz = (const float*)d_in[3];
    const float* Win = (const float*)d_in[4];
    const float* Whr = (const float*)d_in[5];
    const float* Whz = (const float*)d_in[6];
    const float* Whn = (const float*)d_in[7];
    const float* bhr = (const float*)d_in[8];
    const float* bhz = (const float*)d_in[9];
    const float* bhn = (const float*)d_in[10];
    const float* Wd  = (const float*)d_in[11];
    const float* bd  = (const float*)d_in[12];
    float* out = (float*)d_out;

    gru_persistent<<<BB, NT, 0, stream>>>(x, h0, Wir, Wiz, Win, Whr, Whz, Whn,
                                          bhr, bhz, bhn, Wd, bd, out);
}